// Round 15
// baseline (172.015 us; speedup 1.0000x reference)
//
#include <hip/hip_runtime.h>
#include <math.h>

#define NN 1024
#define HD 64
#define NL 3

// ws layout (floats):
#define WTE 0                     // te[64]
#define WTC 64                    // tc[3][64]  = mb + te@mw_t
#define WEC 256                   // ec[64]     = hb1 + te@hw1_te
#define WCV 320                   // c[3][64]   = eb2@mw_m
#define WW  512                   // WT[3][64][128]: col-major folded W (see k_pre)
#define WHI (512 + 3*128*64)      // hi[N][64]
#define WHJ (WHI + NN*HD)         // hj[N][64] (pre-biased with ab1)

__device__ __forceinline__ float fsilu(float x) {
    float e = __expf(-x);
    return x * __builtin_amdgcn_rcpf(1.0f + e);
}
__device__ __forceinline__ float fsilu_acc(float x, float acc) {
    float e = __expf(-x);
    float r = __builtin_amdgcn_rcpf(1.0f + e);
    return fmaf(x, r, acc);            // acc += silu(x), fused
}
__device__ __forceinline__ float fsigmoid(float x) {
    float e = __expf(-x);
    return __builtin_amdgcn_rcpf(1.0f + e);
}

// -------- kernel 0: precompute folded weights + time-embedding tables ------
// Algebra: h' = silu([h,msg,te]@mw + mb), msg = s@ew2 + deg*eb2 + h
//   =>  h' = silu( h@(mw_h+mw_m) + s@(ew2@mw_m) + deg*(eb2@mw_m) + mb+te@mw_t )
// W stored TRANSPOSED: WT[l][h][row], row 0-63 = (mw_h+mw_m)^T, 64-127 = (ew2@mw_m)^T
__global__ __launch_bounds__(256) void k_pre(
    const int* __restrict__ tp,
    const float* __restrict__ tw1, const float* __restrict__ tb1,
    const float* __restrict__ tw2, const float* __restrict__ tb2,
    const float* __restrict__ ew2, const float* __restrict__ eb2,
    const float* __restrict__ mw,  const float* __restrict__ mb,
    const float* __restrict__ hw1, const float* __restrict__ hb1,
    float* __restrict__ ws)
{
    const int b = blockIdx.x, t = threadIdx.x;
    if (b == 0) {
        __shared__ float raw[HD], x1[HD], te[HD];
        if (t < HD) {
            const float tv = (float)(*tp);
            const float fr = __expf((float)(t & 31) * (-logf(10000.0f) / 31.0f));
            const float ang = tv * fr;
            raw[t] = (t < 32) ? sinf(ang) : cosf(ang);
        }
        __syncthreads();
        if (t < HD) {
            float a = tb1[t];
            #pragma unroll 8
            for (int k = 0; k < HD; ++k) a = fmaf(raw[k], tw1[k*HD + t], a);
            x1[t] = fsilu(a);
        }
        __syncthreads();
        if (t < HD) {
            float a = tb2[t];
            #pragma unroll 8
            for (int k = 0; k < HD; ++k) a = fmaf(x1[k], tw2[k*HD + t], a);
            te[t] = a;
            ws[WTE + t] = a;
        }
        __syncthreads();
        if (t < 192) {
            const int l = t >> 6, h = t & 63;
            float a = mb[l*HD + h];          // tc = mb + te@mw_t
            float c = 0.0f;                  // c  = eb2@mw_m
            #pragma unroll 8
            for (int k = 0; k < HD; ++k) {
                a = fmaf(te[k],          mw[(l*3*HD + 2*HD + k)*HD + h], a);
                c = fmaf(eb2[l*HD + k],  mw[(l*3*HD +   HD + k)*HD + h], c);
            }
            ws[WTC + t] = a;
            ws[WCV + t] = c;
        } else {
            const int h = t - 192;           // ec = hb1 + te@hw1_te
            float a = hb1[h];
            #pragma unroll 8
            for (int k = 0; k < HD; ++k) a = fmaf(te[k], hw1[(HD + k)*HD + h], a);
            ws[WEC + h] = a;
        }
    } else {
        const int l = b - 1;
        __shared__ float s_w2[HD*HD];   // ew2[l]
        __shared__ float s_mm[HD*HD];   // mw_m[l]
        for (int o = t; o < HD*HD; o += 256) {
            const int r = o >> 6, h = o & 63;
            s_w2[o] = ew2[l*HD*HD + o];
            const float mm = mw[(l*3*HD + HD + r)*HD + h];
            s_mm[o] = mm;
            // A^T: WT[h][r] = mw_h[r][h] + mw_m[r][h]
            ws[WW + l*HD*128 + h*128 + r] = mw[(l*3*HD + r)*HD + h] + mm;
        }
        __syncthreads();
        // E^T: WT[h][64+r] = sum_k ew2[r][k] * mw_m[k][h]
        const int h = t & 63, r0 = t >> 6;   // each thread: 16 rows, one col
        float acc[16];
        #pragma unroll
        for (int ri = 0; ri < 16; ++ri) acc[ri] = 0.0f;
        for (int k = 0; k < HD; ++k) {
            const float mv = s_mm[k*HD + h];
            #pragma unroll
            for (int ri = 0; ri < 16; ++ri)
                acc[ri] = fmaf(s_w2[(r0*16 + ri)*HD + k], mv, acc[ri]);
        }
        #pragma unroll
        for (int ri = 0; ri < 16; ++ri)
            ws[WW + l*HD*128 + h*128 + 64 + r0*16 + ri] = acc[ri];
    }
}

// -------- kernel 1: per-row fused 3-layer message passing ------------------
__global__ __launch_bounds__(512, 8) void k_main(
    const float* __restrict__ pos, const float* __restrict__ adj,
    const float* __restrict__ nmask,
    const float* __restrict__ pw, const float* __restrict__ pb,
    const float* __restrict__ ew1, const float* __restrict__ eb1,
    const float* __restrict__ aw1, const float* __restrict__ ab1,
    const float* __restrict__ hw1,
    const float* __restrict__ hw2, const float* __restrict__ hb2,
    float* __restrict__ ws, float* __restrict__ out)
{
    __shared__ float4 s_ef[NN];                       // compacted edges 16KB
    __shared__ __align__(16) float s_red[16*NL*HD];   // partials        12KB
    __shared__ __align__(16) float s_s[NL*HD];        // geometry sums
    __shared__ __align__(16) float s_h[HD];
    __shared__ float s_eu[HD];
    __shared__ int   s_nnz;

    const int i = blockIdx.x;
    const int t = threadIdx.x;
    const int lane = t & 63;

    if (t == 0) s_nnz = 0;
    __syncthreads();

    // ---- compact nonzero adj entries + rel/dist (adj is binary 0/1) ----
    const float pix = pos[3*i+0], piy = pos[3*i+1], piz = pos[3*i+2];
    for (int base = 0; base < NN; base += 512) {
        const int j = base + t;
        const bool nz = (adj[i*NN + j] != 0.0f);
        const unsigned long long m = __ballot(nz);
        int wb = 0;
        if (lane == 0) wb = atomicAdd(&s_nnz, __popcll(m));
        wb = __shfl(wb, 0);
        if (nz) {
            const int k = wb + __popcll(m & ((1ull << lane) - 1ull));
            const float dx = pix - pos[3*j+0];
            const float dy = piy - pos[3*j+1];
            const float dz = piz - pos[3*j+2];
            s_ef[k] = make_float4(dx, dy, dz, sqrtf(dx*dx + dy*dy + dz*dz));
        }
    }
    if (t < HD) {   // h0 = pos@pw + pb + te
        float a = pb[t] + ws[WTE + t];
        a = fmaf(pix, pw[0*HD + t], a);
        a = fmaf(piy, pw[1*HD + t], a);
        a = fmaf(piz, pw[2*HD + t], a);
        s_h[t] = a;
    }
    __syncthreads();
    const int nnz = s_nnz;
    const float deg = (float)nnz;        // adj values are exactly 0/1

    // ---- phase 1 (ALL 3 layers, single pass, k-unrolled x2 for ILP):
    //      s_l[h] = sum_{nz j} silu(ef_j @ ew1[l] + eb1[l])
    const int jj = t >> 5;               // 16 j-groups
    const int hp = t & 31;               // cols hp and hp+32
    float w[NL][2][4], bb[NL][2], acc[NL][2];
    #pragma unroll
    for (int l = 0; l < NL; ++l)
        #pragma unroll
        for (int c = 0; c < 2; ++c) {
            const int hc = hp + 32*c;
            #pragma unroll
            for (int m = 0; m < 4; ++m) w[l][c][m] = ew1[(l*4 + m)*HD + hc];
            bb[l][c] = eb1[l*HD + hc];
            acc[l][c] = 0.0f;
        }
    int k = jj;
    for (; k + 16 < nnz; k += 32) {      // 2 edges/iter -> 12 indep. silu chains
        const float4 efa = s_ef[k];
        const float4 efb = s_ef[k + 16];
        #pragma unroll
        for (int l = 0; l < NL; ++l)
            #pragma unroll
            for (int c = 0; c < 2; ++c) {
                float ga = fmaf(efa.x, w[l][c][0], bb[l][c]);
                float gb = fmaf(efb.x, w[l][c][0], bb[l][c]);
                ga = fmaf(efa.y, w[l][c][1], ga);
                gb = fmaf(efb.y, w[l][c][1], gb);
                ga = fmaf(efa.z, w[l][c][2], ga);
                gb = fmaf(efb.z, w[l][c][2], gb);
                ga = fmaf(efa.w, w[l][c][3], ga);
                gb = fmaf(efb.w, w[l][c][3], gb);
                acc[l][c] = fsilu_acc(ga, acc[l][c]);
                acc[l][c] = fsilu_acc(gb, acc[l][c]);
            }
    }
    if (k < nnz) {
        const float4 ef = s_ef[k];
        #pragma unroll
        for (int l = 0; l < NL; ++l)
            #pragma unroll
            for (int c = 0; c < 2; ++c) {
                float g = fmaf(ef.x, w[l][c][0], bb[l][c]);
                g = fmaf(ef.y, w[l][c][1], g);
                g = fmaf(ef.z, w[l][c][2], g);
                g = fmaf(ef.w, w[l][c][3], g);
                acc[l][c] = fsilu_acc(g, acc[l][c]);
            }
    }
    #pragma unroll
    for (int l = 0; l < NL; ++l)
        #pragma unroll
        for (int c = 0; c < 2; ++c)
            s_red[(l*16 + jj)*HD + hp + 32*c] = acc[l][c];
    __syncthreads();
    if (t < NL*HD) {
        const int l = t >> 6, h = t & 63;
        float s = 0.0f;
        #pragma unroll
        for (int g = 0; g < 16; ++g) s += s_red[(l*16 + g)*HD + h];
        s_s[l*HD + h] = s;
    }
    __syncthreads();

    // ---- phase 2: h' = silu( [h|s_l] @ W_l + deg*c_l + tc_l ), W transposed
    const int q = t >> 6, h2 = t & 63;
    for (int l = 0; l < NL; ++l) {
        const float4* wt = (const float4*)(ws + WW + l*HD*128 + h2*128 + q*16);
        const float4 w0 = wt[0], w1 = wt[1], w2 = wt[2], w3 = wt[3];
        const float* xb = (q < 4) ? (const float*)s_h + q*16
                                  : (const float*)s_s + l*HD + (q - 4)*16;
        const float4 x0 = ((const float4*)xb)[0];
        const float4 x1 = ((const float4*)xb)[1];
        const float4 x2 = ((const float4*)xb)[2];
        const float4 x3 = ((const float4*)xb)[3];
        float pm = x0.x*w0.x;
        pm = fmaf(x0.y, w0.y, pm); pm = fmaf(x0.z, w0.z, pm); pm = fmaf(x0.w, w0.w, pm);
        pm = fmaf(x1.x, w1.x, pm); pm = fmaf(x1.y, w1.y, pm);
        pm = fmaf(x1.z, w1.z, pm); pm = fmaf(x1.w, w1.w, pm);
        pm = fmaf(x2.x, w2.x, pm); pm = fmaf(x2.y, w2.y, pm);
        pm = fmaf(x2.z, w2.z, pm); pm = fmaf(x2.w, w2.w, pm);
        pm = fmaf(x3.x, w3.x, pm); pm = fmaf(x3.y, w3.y, pm);
        pm = fmaf(x3.z, w3.z, pm); pm = fmaf(x3.w, w3.w, pm);
        s_red[q*HD + h2] = pm;
        __syncthreads();
        if (t < HD) {
            float a = ws[WTC + l*HD + t];
            a = fmaf(deg, ws[WCV + l*HD + t], a);
            #pragma unroll
            for (int g = 0; g < 8; ++g) a += s_red[g*HD + t];
            s_h[t] = fsilu(a);
        }
        __syncthreads();
    }

    // ---- tail: eps-head hidden + adj-head projections (3 parallel matvecs)
    if (t < 192) {
        const int sel = t >> 6, col = t & 63;
        if (sel == 0) {
            float a = ws[WEC + col];
            #pragma unroll 8
            for (int k2 = 0; k2 < HD; ++k2) a = fmaf(s_h[k2], hw1[k2*HD + col], a);
            s_eu[col] = fsilu(a);
        } else if (sel == 1) {
            float a = 0.0f;
            #pragma unroll 8
            for (int k2 = 0; k2 < HD; ++k2) a = fmaf(s_h[k2], aw1[k2*HD + col], a);
            ws[WHI + i*HD + col] = a;
        } else {
            float a = ab1[col];   // fold ab1 into hj
            #pragma unroll 8
            for (int k2 = 0; k2 < HD; ++k2) a = fmaf(s_h[k2], aw1[(HD + k2)*HD + col], a);
            ws[WHJ + i*HD + col] = a;
        }
    }
    __syncthreads();
    if (t < 3) {
        float e = hb2[t];
        for (int k2 = 0; k2 < HD; ++k2) e = fmaf(s_eu[k2], hw2[k2*3 + t], e);
        out[NN*NN + i*3 + t] = e * nmask[i];
    }
}

// -------- kernel 2: adj head on unordered tile pairs -----------------------
__global__ __launch_bounds__(256, 8) void k_adj(
    const float* __restrict__ ws, const float* __restrict__ nmask,
    const float* __restrict__ aw2, const float* __restrict__ ab2,
    float* __restrict__ out)
{
    __shared__ float4 s_hiI[16*17], s_hjJ[16*17], s_hiJ[16*17], s_hjI[16*17];
    __shared__ float4 s_w[16];
    __shared__ float s_L1[16][17], s_L2[16][17];
    const int T = NN / 16;  // 64 tiles per side
    const int b = blockIdx.x;
    // decode unordered pair (I <= J) from linear index b
    int I = (int)((2.0*T + 1.0 -
                   sqrt((2.0*T + 1.0)*(2.0*T + 1.0) - 8.0*(double)b)) * 0.5);
    if (I < 0) I = 0; if (I > T-1) I = T-1;
    while (I+1 <= T-1 && ((I+1)*T - ((I+1)*I)/2) <= b) ++I;
    while (I > 0 && (I*T - (I*(I-1))/2) > b) --I;
    const int J = I + (b - (I*T - (I*(I-1))/2));
    const int I0 = I*16, J0 = J*16;
    const int t = threadIdx.x;
    const float* hi = ws + WHI;
    const float* hj = ws + WHJ;   // pre-biased with ab1
    if (t < 16) s_w[t] = ((const float4*)aw2)[t];
    // stage hi/hj rows for both tiles (padded [16][17] float4 -> conflict-free)
    for (int idx = t; idx < 4*16*16; idx += 256) {
        const int arr = idx >> 8, rem = idx & 255, r = rem >> 4, qq = rem & 15;
        const float* src = (arr == 0 || arr == 2) ? hi : hj;
        const int rowt = (arr == 0 || arr == 3) ? I0 : J0;
        const float4 v = *reinterpret_cast<const float4*>(src + (rowt + r)*HD + qq*4);
        float4* dst = (arr == 0) ? s_hiI : (arr == 1) ? s_hjJ
                     : (arr == 2) ? s_hiJ : s_hjI;
        dst[r*17 + qq] = v;
    }
    __syncthreads();
    const int r = t >> 4, c = t & 15;
    float l1 = 0.f, l2 = 0.f;
    #pragma unroll
    for (int hq = 0; hq < 16; ++hq) {
        const float4 aI = s_hiI[r*17 + hq];
        const float4 bJ = s_hjJ[c*17 + hq];
        const float4 aJ = s_hiJ[r*17 + hq];
        const float4 bI = s_hjI[c*17 + hq];
        const float4 w  = s_w[hq];
        l1 += fsilu(aI.x + bJ.x)*w.x + fsilu(aI.y + bJ.y)*w.y
            + fsilu(aI.z + bJ.z)*w.z + fsilu(aI.w + bJ.w)*w.w;
        l2 += fsilu(aJ.x + bI.x)*w.x + fsilu(aJ.y + bI.y)*w.y
            + fsilu(aJ.z + bI.z)*w.z + fsilu(aJ.w + bI.w)*w.w;
    }
    const float b2 = ab2[0];
    s_L1[r][c] = l1 + b2;   // logits(I0+r, J0+c)
    s_L2[r][c] = l2 + b2;   // logits(J0+r, I0+c)
    __syncthreads();
    const float v1 = 0.5f*(s_L1[r][c] + s_L2[c][r]);
    const float v2 = 0.5f*(s_L2[r][c] + s_L1[c][r]);
    const int gi1 = I0 + r, gj1 = J0 + c;
    out[gi1*NN + gj1] = fsigmoid(v1) * nmask[gi1] * nmask[gj1];
    const int gi2 = J0 + r, gj2 = I0 + c;
    out[gi2*NN + gj2] = fsigmoid(v2) * nmask[gi2] * nmask[gj2];
}

extern "C" void kernel_launch(void* const* d_in, const int* in_sizes, int n_in,
                              void* d_out, int out_size, void* d_ws, size_t ws_size,
                              hipStream_t stream) {
    const float* pos   = (const float*)d_in[0];
    const float* adjp  = (const float*)d_in[1];
    const float* nmask = (const float*)d_in[2];
    const int*   tp    = (const int*)d_in[3];
    const float* tw1   = (const float*)d_in[4];
    const float* tb1   = (const float*)d_in[5];
    const float* tw2   = (const float*)d_in[6];
    const float* tb2   = (const float*)d_in[7];
    const float* pw    = (const float*)d_in[8];
    const float* pb    = (const float*)d_in[9];
    const float* ew1   = (const float*)d_in[10];
    const float* eb1   = (const float*)d_in[11];
    const float* ew2   = (const float*)d_in[12];
    const float* eb2   = (const float*)d_in[13];
    const float* mw    = (const float*)d_in[14];
    const float* mb    = (const float*)d_in[15];
    const float* aw1   = (const float*)d_in[16];
    const float* ab1   = (const float*)d_in[17];
    const float* aw2   = (const float*)d_in[18];
    const float* ab2   = (const float*)d_in[19];
    const float* hw1   = (const float*)d_in[20];
    const float* hb1   = (const float*)d_in[21];
    const float* hw2   = (const float*)d_in[22];
    const float* hb2   = (const float*)d_in[23];
    float* ws  = (float*)d_ws;
    float* out = (float*)d_out;

    hipLaunchKernelGGL(k_pre, dim3(1 + NL), dim3(256), 0, stream,
                       tp, tw1, tb1, tw2, tb2, ew2, eb2, mw, mb, hw1, hb1, ws);
    hipLaunchKernelGGL(k_main, dim3(NN), dim3(512), 0, stream,
                       pos, adjp, nmask, pw, pb, ew1, eb1, aw1, ab1,
                       hw1, hw2, hb2, ws, out);
    hipLaunchKernelGGL(k_adj, dim3((NN/16)*((NN/16)+1)/2), dim3(256), 0, stream,
                       ws, nmask, aw2, ab2, out);
}